// Round 4
// baseline (351.541 us; speedup 1.0000x reference)
//
#include <hip/hip_runtime.h>

#define D 128
#define BSHIFT 8
#define BSIZE 256        // nodes per fine bucket
#define NBMAX 512        // max buckets (N <= 131072)
#define CHUNK 4096       // edges per block in scatter
#define SRCBITS 17
#define SRCMASK 0x1FFFF

typedef unsigned int uint;
typedef unsigned short u16;
typedef unsigned char u8;
typedef __attribute__((ext_vector_type(8))) short short8;
typedef __attribute__((ext_vector_type(4))) float floatx4;

// ---- bf16 helpers (RNE) ----
__device__ __forceinline__ u16 f2bf(float f) {
    union { float f; uint u; } c; c.f = f;
    uint u = c.u;
    u += 0x7FFFu + ((u >> 16) & 1u);
    return (u16)(u >> 16);
}
__device__ __forceinline__ float bflo(uint u) {
    union { uint u; float f; } c; c.u = u << 16; return c.f;
}
__device__ __forceinline__ float bfhi(uint u) {
    union { uint u; float f; } c; c.u = u & 0xFFFF0000u; return c.f;
}

// ------- init per-bucket cursors (dst-keyed and src-keyed) to padded bases -
__global__ __launch_bounds__(NBMAX) void init_cursor_kernel(
    int* __restrict__ cursor_d, int* __restrict__ cursor_s, int NB, int cap)
{
    int t = threadIdx.x;
    if (t < NB) { cursor_d[t] = t * cap; cursor_s[t] = t * cap; }
}

// ------- single edge pass, NO per-edge global atomics ----------------------
__global__ __launch_bounds__(256) void scatter_direct_kernel(
    const int* __restrict__ src, const int* __restrict__ dst,
    int* __restrict__ cursor_d, int* __restrict__ cursor_s,
    int* __restrict__ packed, u8* __restrict__ sbytes, int E, int cap)
{
    __shared__ int lcnt_d[NBMAX], lbase_d[NBMAX];
    __shared__ int lcnt_s[NBMAX], lbase_s[NBMAX];
    __shared__ int dbuf[CHUNK];      // 16 KB dst cache: read global once
    __shared__ int sbuf[CHUNK];      // 16 KB src cache: read global once
    int t = threadIdx.x;
    for (int j = t; j < NBMAX; j += 256) { lcnt_d[j] = 0; lcnt_s[j] = 0; }
    __syncthreads();
    int base = blockIdx.x * CHUNK;
    int end  = min(base + CHUNK, E);
    for (int i = base + t; i < end; i += 256) {
        int d = dst[i];
        int s = src[i];
        dbuf[i - base] = d;
        sbuf[i - base] = s;
        atomicAdd(&lcnt_d[d >> BSHIFT], 1);
        atomicAdd(&lcnt_s[s >> BSHIFT], 1);
    }
    __syncthreads();
    int rot = (blockIdx.x * 97) & (NBMAX - 1);
    for (int j = t; j < NBMAX; j += 256) {
        int jj = (j + rot) & (NBMAX - 1);
        int c = lcnt_d[jj];
        lbase_d[jj] = c ? atomicAdd(&cursor_d[jj], c) : 0;
        lcnt_d[jj] = 0;
        c = lcnt_s[jj];
        lbase_s[jj] = c ? atomicAdd(&cursor_s[jj], c) : 0;
        lcnt_s[jj] = 0;
    }
    __syncthreads();
    for (int i = base + t; i < end; i += 256) {
        int d = dbuf[i - base];
        int s = sbuf[i - base];
        int bd = d >> BSHIFT;
        int slot = lbase_d[bd] + atomicAdd(&lcnt_d[bd], 1);
        if (slot < (bd + 1) * cap)           // overflow guard (cap = 2x mean)
            packed[slot] = ((d & (BSIZE - 1)) << SRCBITS) | s;
        int bs = s >> BSHIFT;
        int slot2 = lbase_s[bs] + atomicAdd(&lcnt_s[bs], 1);
        if (slot2 < (bs + 1) * cap)
            sbytes[slot2] = (u8)(s & (BSIZE - 1));
    }
}

// ------- scan dst-bucket counts (one small block) --------------------------
__global__ __launch_bounds__(NBMAX) void bucket_scan_kernel(
    const int* __restrict__ cursor, int* __restrict__ bucket_ptr,
    int* __restrict__ row_ptr, int NB, int N, int E, int cap)
{
    __shared__ int sh[NBMAX];
    int t = threadIdx.x;
    int c = (t < NB) ? min(cursor[t] - t * cap, cap) : 0;
    sh[t] = c;
    __syncthreads();
    for (int off = 1; off < NBMAX; off <<= 1) {
        int v = (t >= off) ? sh[t - off] : 0;
        __syncthreads();
        sh[t] += v;
        __syncthreads();
    }
    if (t < NB) bucket_ptr[t] = sh[t] - c;   // exclusive prefix
    if (t == 0) row_ptr[N] = E;
}

// ------- src degrees from byte buckets: LDS histogram, coalesced out -------
__global__ __launch_bounds__(256) void count_src_kernel(
    const u8* __restrict__ sbytes, const int* __restrict__ cursor_s,
    float* __restrict__ norm_src, int N, int cap)
{
    __shared__ uint hist[BSIZE];
    int b = blockIdx.x, t = threadIdx.x;
    int pbase = b * cap;                      // cap multiple of 1024 -> aligned
    int cnt = min(cursor_s[b] - pbase, cap);
    hist[t] = 0;
    __syncthreads();
    const uint* w = (const uint*)(sbytes + pbase);
    int nw = cnt >> 2;
    for (int i = t; i < nw; i += 256) {
        uint v = w[i];
        atomicAdd(&hist[v & 255u], 1u);
        atomicAdd(&hist[(v >> 8) & 255u], 1u);
        atomicAdd(&hist[(v >> 16) & 255u], 1u);
        atomicAdd(&hist[v >> 24], 1u);
    }
    for (int i = (nw << 2) + t; i < cnt; i += 256)
        atomicAdd(&hist[sbytes[pbase + i]], 1u);
    __syncthreads();
    int node = (b << BSHIFT) + t;
    if (node < N) norm_src[node] = rsqrtf((float)max((int)hist[t], 1));
}

// ------- per-bucket fine CSR: row_ptr, norm_dst, compact col ---------------
__global__ __launch_bounds__(256) void fine_place_kernel(
    const int* __restrict__ packed, const int* __restrict__ cursor,
    const int* __restrict__ bucket_ptr, int* __restrict__ row_ptr,
    float* __restrict__ norm_dst, int* __restrict__ col, int N, int cap)
{
    __shared__ int lcnt[BSIZE];
    __shared__ int lptr[BSIZE];
    int b = blockIdx.x, t = threadIdx.x;
    int nbase = b << BSHIFT;
    int pbase = b * cap;
    int cnt   = min(cursor[b] - pbase, cap);
    int obase = bucket_ptr[b];
    lcnt[t] = 0;
    __syncthreads();
    for (int i = t; i < cnt; i += 256)
        atomicAdd(&lcnt[packed[pbase + i] >> SRCBITS], 1);
    __syncthreads();
    for (int off = 1; off < BSIZE; off <<= 1) {
        int v = (t >= off) ? lcnt[t - off] : 0;
        __syncthreads();
        lcnt[t] += v;
        __syncthreads();
    }
    {
        int incl = lcnt[t];
        int excl = (t == 0) ? 0 : lcnt[t - 1];
        int node = nbase + t;
        if (node < N) {
            row_ptr[node] = obase + excl;
            norm_dst[node] = rsqrtf((float)max(incl - excl, 1));
        }
        lptr[t] = obase + excl;
    }
    __syncthreads();
    for (int i = t; i < cnt; i += 256) {
        int p = packed[pbase + i];
        int slot = atomicAdd(&lptr[p >> SRCBITS], 1);
        col[slot] = p & SRCMASK;
    }
}

// ------- fp32 -> bf16 (RNE), float4 -> ushort4 -----------------------------
__global__ __launch_bounds__(256) void convert_bf16_kernel(
    const float* __restrict__ x, u16* __restrict__ y, int total4)
{
    int i = blockIdx.x * 256 + threadIdx.x;
    if (i >= total4) return;
    float4 v = ((const float4*)x)[i];
    ushort4 o;
    o.x = f2bf(v.x); o.y = f2bf(v.y); o.z = f2bf(v.z); o.w = f2bf(v.w);
    ((ushort4*)y)[i] = o;
}

// ------- W [k][n] fp32 -> W_T [n][k] bf16 ----------------------------------
__global__ __launch_bounds__(256) void convert_wT_kernel(
    const float* __restrict__ W, u16* __restrict__ WT)
{
    int i = blockIdx.x * 256 + threadIdx.x;   // i = k*128 + n
    int k = i >> 7, n = i & 127;
    WT[n * 128 + k] = f2bf(W[i]);
}

// ---------- FUSED: gather-aggregate -> LDS -> MFMA GEMM -> relu(out) -------
// Block = 256 threads = 16 dst nodes. W fragments + bias preloaded into
// registers BEFORE the gather (L2 latency hides under the 60us gather).
// Epilogue goes through a padded f32 LDS tile so the global write is one
// contiguous coalesced burst per block (32B-chunk scatter was 2x WRITE).
template <bool BF16_OUT>
__global__ __launch_bounds__(256) void agg_gemm_kernel(
    const u16* __restrict__ hs, const int* __restrict__ row_ptr,
    const int* __restrict__ col, const float* __restrict__ norm_src,
    const float* __restrict__ norm_dst, const u16* __restrict__ WT,
    const float* __restrict__ bias, float* __restrict__ out_f,
    u16* __restrict__ out_b, int N)
{
    __shared__ u16 rows[16][140];    // stride 70 dwords (== 6 mod 32): low-conflict A-frag reads
    __shared__ float outt[16][132];  // padded f32 out tile for coalesced store
    int wave = threadIdx.x >> 6;
    int lane = threadIdx.x & 63;
    int g    = lane >> 4;     // edge-group 0..3 (gather); quad (MFMA)
    int l16  = lane & 15;     // position within row (gather); m16 (MFMA)
    int nbase = blockIdx.x * 16;
    const uint4* h4 = (const uint4*)hs;

    // ---- preload W fragments + bias (registers, latency hidden by gather) --
    int c0 = wave * 2, c1 = wave * 2 + 1;
    short8 wb0[4], wb1[4];
    #pragma unroll
    for (int q = 0; q < 4; ++q) {
        wb0[q] = *(const short8*)(WT + (size_t)(c0 * 16 + l16) * D + q * 32 + g * 8);
        wb1[q] = *(const short8*)(WT + (size_t)(c1 * 16 + l16) * D + q * 32 + g * 8);
    }
    float bv0 = bias[c0 * 16 + l16];
    float bv1 = bias[c1 * 16 + l16];

    // ---- gather phase: each wave aggregates 4 nodes -----------------------
    #pragma unroll
    for (int j = 0; j < 4; ++j) {
        int n = nbase + wave * 4 + j;
        float acc[8];
        #pragma unroll
        for (int k = 0; k < 8; ++k) acc[k] = 0.f;

        if (n < N) {
            int beg = row_ptr[n], end = row_ptr[n + 1];
            int i = beg + g;
            for (; i + 4 < end; i += 8) {
                int s0 = col[i], s1 = col[i + 4];
                float ns0 = norm_src[s0], ns1 = norm_src[s1];
                uint4 v0 = h4[(size_t)s0 * 16 + l16];
                uint4 v1 = h4[(size_t)s1 * 16 + l16];
                acc[0] = fmaf(bflo(v0.x), ns0, acc[0]);
                acc[1] = fmaf(bfhi(v0.x), ns0, acc[1]);
                acc[2] = fmaf(bflo(v0.y), ns0, acc[2]);
                acc[3] = fmaf(bfhi(v0.y), ns0, acc[3]);
                acc[4] = fmaf(bflo(v0.z), ns0, acc[4]);
                acc[5] = fmaf(bfhi(v0.z), ns0, acc[5]);
                acc[6] = fmaf(bflo(v0.w), ns0, acc[6]);
                acc[7] = fmaf(bfhi(v0.w), ns0, acc[7]);
                acc[0] = fmaf(bflo(v1.x), ns1, acc[0]);
                acc[1] = fmaf(bfhi(v1.x), ns1, acc[1]);
                acc[2] = fmaf(bflo(v1.y), ns1, acc[2]);
                acc[3] = fmaf(bfhi(v1.y), ns1, acc[3]);
                acc[4] = fmaf(bflo(v1.z), ns1, acc[4]);
                acc[5] = fmaf(bfhi(v1.z), ns1, acc[5]);
                acc[6] = fmaf(bflo(v1.w), ns1, acc[6]);
                acc[7] = fmaf(bfhi(v1.w), ns1, acc[7]);
            }
            if (i < end) {
                int s = col[i];
                float ns = norm_src[s];
                uint4 v = h4[(size_t)s * 16 + l16];
                acc[0] = fmaf(bflo(v.x), ns, acc[0]);
                acc[1] = fmaf(bfhi(v.x), ns, acc[1]);
                acc[2] = fmaf(bflo(v.y), ns, acc[2]);
                acc[3] = fmaf(bfhi(v.y), ns, acc[3]);
                acc[4] = fmaf(bflo(v.z), ns, acc[4]);
                acc[5] = fmaf(bfhi(v.z), ns, acc[5]);
                acc[6] = fmaf(bflo(v.w), ns, acc[6]);
                acc[7] = fmaf(bfhi(v.w), ns, acc[7]);
            }
        }

        #pragma unroll
        for (int k = 0; k < 8; ++k) {
            acc[k] += __shfl_xor(acc[k], 16, 64);
            acc[k] += __shfl_xor(acc[k], 32, 64);
        }

        if (g == 0) {
            float nd = (n < N) ? norm_dst[n] : 0.f;
            ushort4 lo, hi;
            lo.x = f2bf(acc[0] * nd); lo.y = f2bf(acc[1] * nd);
            lo.z = f2bf(acc[2] * nd); lo.w = f2bf(acc[3] * nd);
            hi.x = f2bf(acc[4] * nd); hi.y = f2bf(acc[5] * nd);
            hi.z = f2bf(acc[6] * nd); hi.w = f2bf(acc[7] * nd);
            ushort4* o = (ushort4*)&rows[wave * 4 + j][l16 * 8];
            o[0] = lo; o[1] = hi;
        }
    }
    __syncthreads();

    // ---- MFMA phase: wave handles col-tiles c0,c1 (pure LDS + regs) -------
    int m16 = l16, quad = g;
    floatx4 accm0 = (floatx4){0.f, 0.f, 0.f, 0.f};
    floatx4 accm1 = (floatx4){0.f, 0.f, 0.f, 0.f};
    #pragma unroll
    for (int q = 0; q < 4; ++q) {
        short8 a = *(const short8*)&rows[m16][q * 32 + quad * 8];
        accm0 = __builtin_amdgcn_mfma_f32_16x16x32_bf16(a, wb0[q], accm0, 0, 0, 0);
        accm1 = __builtin_amdgcn_mfma_f32_16x16x32_bf16(a, wb1[q], accm1, 0, 0, 0);
    }

    // bias + relu -> padded LDS out tile
    #pragma unroll
    for (int r = 0; r < 4; ++r) {
        outt[quad * 4 + r][c0 * 16 + m16] = fmaxf(accm0[r] + bv0, 0.f);
        outt[quad * 4 + r][c1 * 16 + m16] = fmaxf(accm1[r] + bv1, 0.f);
    }
    __syncthreads();

    // ---- coalesced contiguous store of the 16x128 tile --------------------
    int t = threadIdx.x;
    if (BF16_OUT) {
        // thread t -> 8 elems of row (t>>4), one uint4 store, 4KB burst/block
        int r = t >> 4, c = (t & 15) * 8;
        if (nbase + r < N) {
            ushort4 o0, o1;
            o0.x = f2bf(outt[r][c + 0]); o0.y = f2bf(outt[r][c + 1]);
            o0.z = f2bf(outt[r][c + 2]); o0.w = f2bf(outt[r][c + 3]);
            o1.x = f2bf(outt[r][c + 4]); o1.y = f2bf(outt[r][c + 5]);
            o1.z = f2bf(outt[r][c + 6]); o1.w = f2bf(outt[r][c + 7]);
            ushort4* o = (ushort4*)(out_b + (size_t)(nbase + r) * D + c);
            o[0] = o0; o[1] = o1;
        }
    } else {
        // two float4 passes, 8KB contiguous burst/block
        #pragma unroll
        for (int p = 0; p < 2; ++p) {
            int e = p * 1024 + t * 4;
            int r = e >> 7, c = e & 127;
            if (nbase + r < N) {
                float4 v;
                v.x = outt[r][c + 0]; v.y = outt[r][c + 1];
                v.z = outt[r][c + 2]; v.w = outt[r][c + 3];
                *(float4*)(out_f + (size_t)nbase * D + e) = v;
            }
        }
    }
}

extern "C" void kernel_launch(void* const* d_in, const int* in_sizes, int n_in,
                              void* d_out, int out_size, void* d_ws, size_t ws_size,
                              hipStream_t stream)
{
    const float* features = (const float*)d_in[0];
    const int*   src      = (const int*)d_in[1];
    const int*   dst      = (const int*)d_in[2];
    const float* W1       = (const float*)d_in[3];
    const float* b1       = (const float*)d_in[4];
    const float* W2       = (const float*)d_in[5];
    const float* b2       = (const float*)d_in[6];
    float*       out      = (float*)d_out;

    const int N = in_sizes[0] / D;
    const int E = in_sizes[1];
    const int NB = (N + BSIZE - 1) >> BSHIFT;

    // padded bucket capacity: 2x mean, multiple of 1024;
    // bounded so packed(4B) + sbytes(1B) fit the N*D bf16 region (5B/slot).
    int cap = ((2 * (E / NB) + 2047) / 1024) * 1024;
    int cap_max = (int)(((size_t)N * D * 2 / (5 * NB)) / 1024 * 1024);
    if (cap > cap_max) cap = cap_max;

    // workspace layout
    u16*   scratch  = (u16*)d_ws;                   // N*D bf16 region (packed+sbytes)
    int*   packed   = (int*)scratch;                // NB*cap ints
    u8*    sbytes   = (u8*)(packed + (size_t)NB * cap);  // NB*cap bytes
    u16*   feat_bf  = scratch + (size_t)N * D;      // N*D bf16
    u16*   hs_bf    = feat_bf + (size_t)N * D;      // N*D bf16
    u16*   wT1      = hs_bf + (size_t)N * D;        // 16384 bf16
    u16*   wT2      = wT1 + D * D;                  // 16384 bf16
    float* norm_src = (float*)(wT2 + D * D);        // N
    float* norm_dst = norm_src + N;                 // N
    int*   iws          = (int*)(norm_dst + N);
    int*   row_ptr      = iws;                      // N+1
    int*   col          = row_ptr + N + 1;          // E
    int*   bucket_ptr   = col + E;                  // NBMAX+1
    int*   cursor_d     = bucket_ptr + NBMAX + 1;   // NBMAX
    int*   cursor_s     = cursor_d + NBMAX;         // NBMAX

    const int ebk = (E + CHUNK - 1) / CHUNK;
    const int fuse_blocks = (N + 15) / 16;
    const int cv_blocks   = (N * 32 + 255) / 256;
    const int wt_blocks   = (D * D + 255) / 256;

    // ---- CSR build: one edge pass (zero per-edge global atomics) ----
    init_cursor_kernel<<<1, NBMAX, 0, stream>>>(cursor_d, cursor_s, NB, cap);
    scatter_direct_kernel<<<ebk, 256, 0, stream>>>(src, dst, cursor_d, cursor_s, packed, sbytes, E, cap);
    bucket_scan_kernel<<<1, NBMAX, 0, stream>>>(cursor_d, bucket_ptr, row_ptr, NB, N, E, cap);
    count_src_kernel<<<NB, 256, 0, stream>>>(sbytes, cursor_s, norm_src, N, cap);
    fine_place_kernel<<<NB, 256, 0, stream>>>(packed, cursor_d, bucket_ptr, row_ptr, norm_dst, col, N, cap);
    convert_bf16_kernel<<<cv_blocks, 256, 0, stream>>>(features, feat_bf, N * 32);
    convert_wT_kernel<<<wt_blocks, 256, 0, stream>>>(W1, wT1);
    convert_wT_kernel<<<wt_blocks, 256, 0, stream>>>(W2, wT2);

    // ---- layer 1 (fused aggregate+GEMM) ----
    agg_gemm_kernel<true><<<fuse_blocks, 256, 0, stream>>>(
        feat_bf, row_ptr, col, norm_src, norm_dst, wT1, b1, nullptr, hs_bf, N);

    // ---- layer 2 (fused aggregate+GEMM) ----
    agg_gemm_kernel<false><<<fuse_blocks, 256, 0, stream>>>(
        hs_bf, row_ptr, col, norm_src, norm_dst, wT2, b2, out, nullptr, N);
}

// Round 5
// 333.954 us; speedup vs baseline: 1.0527x; 1.0527x over previous
//
#include <hip/hip_runtime.h>

#define D 128
#define BSHIFT 8
#define BSIZE 256        // nodes per fine bucket
#define NBMAX 512        // max buckets (N <= 131072)
#define CHUNK 4096       // edges per block in scatter
#define SRCBITS 17
#define SRCMASK 0x1FFFF

typedef unsigned int uint;
typedef unsigned short u16;
typedef unsigned char u8;
typedef __attribute__((ext_vector_type(8))) short short8;
typedef __attribute__((ext_vector_type(4))) float floatx4;

// ---- bf16 helpers (RNE) ----
__device__ __forceinline__ u16 f2bf(float f) {
    union { float f; uint u; } c; c.f = f;
    uint u = c.u;
    u += 0x7FFFu + ((u >> 16) & 1u);
    return (u16)(u >> 16);
}
__device__ __forceinline__ float bflo(uint u) {
    union { uint u; float f; } c; c.u = u << 16; return c.f;
}
__device__ __forceinline__ float bfhi(uint u) {
    union { uint u; float f; } c; c.u = u & 0xFFFF0000u; return c.f;
}

// ------- setup: W1/W2 transpose+convert, cursor init (one launch) ----------
__global__ __launch_bounds__(256) void setup_kernel(
    const float* __restrict__ W1, const float* __restrict__ W2,
    u16* __restrict__ wT1, u16* __restrict__ wT2,
    int* __restrict__ cursor_d, int* __restrict__ cursor_s, int NB, int cap)
{
    int b = blockIdx.x, t = threadIdx.x;
    if (b < 64) {
        int i = b * 256 + t;                 // i = k*128 + n
        int k = i >> 7, n = i & 127;
        wT1[n * 128 + k] = f2bf(W1[i]);
    } else if (b < 128) {
        int i = (b - 64) * 256 + t;
        int k = i >> 7, n = i & 127;
        wT2[n * 128 + k] = f2bf(W2[i]);
    } else {
        for (int j = t; j < NB; j += 256) {
            cursor_d[j] = j * cap;
            cursor_s[j] = j * cap;
        }
    }
}

// ------- single edge pass, NO per-edge global atomics ----------------------
__global__ __launch_bounds__(256) void scatter_direct_kernel(
    const int* __restrict__ src, const int* __restrict__ dst,
    int* __restrict__ cursor_d, int* __restrict__ cursor_s,
    int* __restrict__ packed, u8* __restrict__ sbytes, int E, int cap)
{
    __shared__ int lcnt_d[NBMAX], lbase_d[NBMAX];
    __shared__ int lcnt_s[NBMAX], lbase_s[NBMAX];
    __shared__ int dbuf[CHUNK];      // 16 KB dst cache: read global once
    __shared__ int sbuf[CHUNK];      // 16 KB src cache: read global once
    int t = threadIdx.x;
    for (int j = t; j < NBMAX; j += 256) { lcnt_d[j] = 0; lcnt_s[j] = 0; }
    __syncthreads();
    int base = blockIdx.x * CHUNK;
    int end  = min(base + CHUNK, E);
    for (int i = base + t; i < end; i += 256) {
        int d = dst[i];
        int s = src[i];
        dbuf[i - base] = d;
        sbuf[i - base] = s;
        atomicAdd(&lcnt_d[d >> BSHIFT], 1);
        atomicAdd(&lcnt_s[s >> BSHIFT], 1);
    }
    __syncthreads();
    int rot = (blockIdx.x * 97) & (NBMAX - 1);
    for (int j = t; j < NBMAX; j += 256) {
        int jj = (j + rot) & (NBMAX - 1);
        int c = lcnt_d[jj];
        lbase_d[jj] = c ? atomicAdd(&cursor_d[jj], c) : 0;
        lcnt_d[jj] = 0;
        c = lcnt_s[jj];
        lbase_s[jj] = c ? atomicAdd(&cursor_s[jj], c) : 0;
        lcnt_s[jj] = 0;
    }
    __syncthreads();
    for (int i = base + t; i < end; i += 256) {
        int d = dbuf[i - base];
        int s = sbuf[i - base];
        int bd = d >> BSHIFT;
        int slot = lbase_d[bd] + atomicAdd(&lcnt_d[bd], 1);
        if (slot < (bd + 1) * cap)           // overflow guard (cap = 2x mean)
            packed[slot] = ((d & (BSIZE - 1)) << SRCBITS) | s;
        int bs = s >> BSHIFT;
        int slot2 = lbase_s[bs] + atomicAdd(&lcnt_s[bs], 1);
        if (slot2 < (bs + 1) * cap)
            sbytes[slot2] = (u8)(s & (BSIZE - 1));
    }
}

// ------- scan dst-bucket counts (one small block) --------------------------
__global__ __launch_bounds__(NBMAX) void bucket_scan_kernel(
    const int* __restrict__ cursor, int* __restrict__ bucket_ptr,
    int* __restrict__ row_ptr, int NB, int N, int E, int cap)
{
    __shared__ int sh[NBMAX];
    int t = threadIdx.x;
    int c = (t < NB) ? min(cursor[t] - t * cap, cap) : 0;
    sh[t] = c;
    __syncthreads();
    for (int off = 1; off < NBMAX; off <<= 1) {
        int v = (t >= off) ? sh[t - off] : 0;
        __syncthreads();
        sh[t] += v;
        __syncthreads();
    }
    if (t < NB) bucket_ptr[t] = sh[t] - c;   // exclusive prefix
    if (t == 0) row_ptr[N] = E;
}

// ------- fused per-bucket: fine CSR + src-degree hist + feature convert ----
// Block b: (a) dst-bucket b -> row_ptr/norm_dst/col, (b) src-bucket b ->
// norm_src via LDS byte-histogram, (c) converts its 1/NB slice of features
// to bf16 (overlaps the serial convert kernel with fine_place's stalls).
__global__ __launch_bounds__(256) void fine_place_kernel(
    const int* __restrict__ packed, const u8* __restrict__ sbytes,
    const int* __restrict__ cursor_d, const int* __restrict__ cursor_s,
    const int* __restrict__ bucket_ptr, int* __restrict__ row_ptr,
    float* __restrict__ norm_dst, float* __restrict__ norm_src,
    int* __restrict__ col,
    const float* __restrict__ feat, u16* __restrict__ feat_bf, int total4,
    int N, int cap)
{
    __shared__ int lcnt[BSIZE];
    __shared__ int lptr[BSIZE];
    __shared__ uint hist[BSIZE];
    int b = blockIdx.x, t = threadIdx.x;
    int nbase = b << BSHIFT;
    int pbase = b * cap;
    int cnt   = min(cursor_d[b] - pbase, cap);
    int scnt  = min(cursor_s[b] - pbase, cap);
    int obase = bucket_ptr[b];
    lcnt[t] = 0;
    hist[t] = 0;
    __syncthreads();
    for (int i = t; i < cnt; i += 256)
        atomicAdd(&lcnt[packed[pbase + i] >> SRCBITS], 1);
    // src-degree histogram from byte bucket (uint4-packed reads)
    {
        const uint* w = (const uint*)(sbytes + pbase);  // cap mult of 1024 -> aligned
        int nw = scnt >> 2;
        for (int i = t; i < nw; i += 256) {
            uint v = w[i];
            atomicAdd(&hist[v & 255u], 1u);
            atomicAdd(&hist[(v >> 8) & 255u], 1u);
            atomicAdd(&hist[(v >> 16) & 255u], 1u);
            atomicAdd(&hist[v >> 24], 1u);
        }
        for (int i = (nw << 2) + t; i < scnt; i += 256)
            atomicAdd(&hist[sbytes[pbase + i]], 1u);
    }
    __syncthreads();
    for (int off = 1; off < BSIZE; off <<= 1) {
        int v = (t >= off) ? lcnt[t - off] : 0;
        __syncthreads();
        lcnt[t] += v;
        __syncthreads();
    }
    {
        int incl = lcnt[t];
        int excl = (t == 0) ? 0 : lcnt[t - 1];
        int node = nbase + t;
        if (node < N) {
            row_ptr[node] = obase + excl;
            norm_dst[node] = rsqrtf((float)max(incl - excl, 1));
            norm_src[node] = rsqrtf((float)max((int)hist[t], 1));
        }
        lptr[t] = obase + excl;
    }
    __syncthreads();
    for (int i = t; i < cnt; i += 256) {
        int p = packed[pbase + i];
        int slot = atomicAdd(&lptr[p >> SRCBITS], 1);
        col[slot] = p & SRCMASK;
    }
    // ---- feature fp32 -> bf16 slice (independent, streams alongside) ----
    int per = (total4 + (int)gridDim.x - 1) / (int)gridDim.x;
    int lo = b * per, hi = min(lo + per, total4);
    for (int i = lo + t; i < hi; i += 256) {
        float4 v = ((const float4*)feat)[i];
        ushort4 o;
        o.x = f2bf(v.x); o.y = f2bf(v.y); o.z = f2bf(v.z); o.w = f2bf(v.w);
        ((ushort4*)feat_bf)[i] = o;
    }
}

// ---------- FUSED: gather-aggregate -> LDS -> MFMA GEMM -> relu(out) -------
// Round-3 structure (VGPR 24, occupancy ~72%): W loaded from global in the
// MFMA phase. Round-4's coalesced epilogue kept, but outt UNIONs over rows
// (rows dead after the MFMA a-frag reads; extra barrier sequences reuse).
template <bool BF16_OUT>
__global__ __launch_bounds__(256) void agg_gemm_kernel(
    const u16* __restrict__ hs, const int* __restrict__ row_ptr,
    const int* __restrict__ col, const float* __restrict__ norm_src,
    const float* __restrict__ norm_dst, const u16* __restrict__ WT,
    const float* __restrict__ bias, float* __restrict__ out_f,
    u16* __restrict__ out_b, int N)
{
    __shared__ __align__(16) char smem[16 * 132 * 4];   // 8448B union
    u16   (*rows)[140] = (u16 (*)[140])smem;            // 4480B live in gather
    float (*outt)[132] = (float (*)[132])smem;          // 8448B live in epilogue
    int wave = threadIdx.x >> 6;
    int lane = threadIdx.x & 63;
    int g    = lane >> 4;     // edge-group 0..3 (gather); quad (MFMA)
    int l16  = lane & 15;     // position within row (gather); m16 (MFMA)
    int nbase = blockIdx.x * 16;
    const uint4* h4 = (const uint4*)hs;

    // ---- gather phase: each wave aggregates 4 nodes -----------------------
    #pragma unroll
    for (int j = 0; j < 4; ++j) {
        int n = nbase + wave * 4 + j;
        float acc[8];
        #pragma unroll
        for (int k = 0; k < 8; ++k) acc[k] = 0.f;

        if (n < N) {
            int beg = row_ptr[n], end = row_ptr[n + 1];
            int i = beg + g;
            for (; i + 4 < end; i += 8) {
                int s0 = col[i], s1 = col[i + 4];
                float ns0 = norm_src[s0], ns1 = norm_src[s1];
                uint4 v0 = h4[(size_t)s0 * 16 + l16];
                uint4 v1 = h4[(size_t)s1 * 16 + l16];
                acc[0] = fmaf(bflo(v0.x), ns0, acc[0]);
                acc[1] = fmaf(bfhi(v0.x), ns0, acc[1]);
                acc[2] = fmaf(bflo(v0.y), ns0, acc[2]);
                acc[3] = fmaf(bfhi(v0.y), ns0, acc[3]);
                acc[4] = fmaf(bflo(v0.z), ns0, acc[4]);
                acc[5] = fmaf(bfhi(v0.z), ns0, acc[5]);
                acc[6] = fmaf(bflo(v0.w), ns0, acc[6]);
                acc[7] = fmaf(bfhi(v0.w), ns0, acc[7]);
                acc[0] = fmaf(bflo(v1.x), ns1, acc[0]);
                acc[1] = fmaf(bfhi(v1.x), ns1, acc[1]);
                acc[2] = fmaf(bflo(v1.y), ns1, acc[2]);
                acc[3] = fmaf(bfhi(v1.y), ns1, acc[3]);
                acc[4] = fmaf(bflo(v1.z), ns1, acc[4]);
                acc[5] = fmaf(bfhi(v1.z), ns1, acc[5]);
                acc[6] = fmaf(bflo(v1.w), ns1, acc[6]);
                acc[7] = fmaf(bfhi(v1.w), ns1, acc[7]);
            }
            if (i < end) {
                int s = col[i];
                float ns = norm_src[s];
                uint4 v = h4[(size_t)s * 16 + l16];
                acc[0] = fmaf(bflo(v.x), ns, acc[0]);
                acc[1] = fmaf(bfhi(v.x), ns, acc[1]);
                acc[2] = fmaf(bflo(v.y), ns, acc[2]);
                acc[3] = fmaf(bfhi(v.y), ns, acc[3]);
                acc[4] = fmaf(bflo(v.z), ns, acc[4]);
                acc[5] = fmaf(bfhi(v.z), ns, acc[5]);
                acc[6] = fmaf(bflo(v.w), ns, acc[6]);
                acc[7] = fmaf(bfhi(v.w), ns, acc[7]);
            }
        }

        #pragma unroll
        for (int k = 0; k < 8; ++k) {
            acc[k] += __shfl_xor(acc[k], 16, 64);
            acc[k] += __shfl_xor(acc[k], 32, 64);
        }

        if (g == 0) {
            float nd = (n < N) ? norm_dst[n] : 0.f;
            ushort4 lo, hi;
            lo.x = f2bf(acc[0] * nd); lo.y = f2bf(acc[1] * nd);
            lo.z = f2bf(acc[2] * nd); lo.w = f2bf(acc[3] * nd);
            hi.x = f2bf(acc[4] * nd); hi.y = f2bf(acc[5] * nd);
            hi.z = f2bf(acc[6] * nd); hi.w = f2bf(acc[7] * nd);
            ushort4* o = (ushort4*)&rows[wave * 4 + j][l16 * 8];
            o[0] = lo; o[1] = hi;
        }
    }
    __syncthreads();

    // ---- MFMA phase: wave handles col-tiles c0,c1 (W from global/L2) ------
    int m16 = l16, quad = g;
    int c0 = wave * 2, c1 = wave * 2 + 1;
    floatx4 accm0 = (floatx4){0.f, 0.f, 0.f, 0.f};
    floatx4 accm1 = (floatx4){0.f, 0.f, 0.f, 0.f};
    #pragma unroll
    for (int q = 0; q < 4; ++q) {
        short8 a = *(const short8*)&rows[m16][q * 32 + quad * 8];
        short8 b0 = *(const short8*)(WT + (size_t)(c0 * 16 + m16) * D + q * 32 + quad * 8);
        short8 b1 = *(const short8*)(WT + (size_t)(c1 * 16 + m16) * D + q * 32 + quad * 8);
        accm0 = __builtin_amdgcn_mfma_f32_16x16x32_bf16(a, b0, accm0, 0, 0, 0);
        accm1 = __builtin_amdgcn_mfma_f32_16x16x32_bf16(a, b1, accm1, 0, 0, 0);
    }
    float bv0 = bias[c0 * 16 + m16];
    float bv1 = bias[c1 * 16 + m16];
    __syncthreads();   // all rows-reads done; safe to overwrite union

    #pragma unroll
    for (int r = 0; r < 4; ++r) {
        outt[quad * 4 + r][c0 * 16 + m16] = fmaxf(accm0[r] + bv0, 0.f);
        outt[quad * 4 + r][c1 * 16 + m16] = fmaxf(accm1[r] + bv1, 0.f);
    }
    __syncthreads();

    // ---- coalesced contiguous store of the 16x128 tile --------------------
    int t = threadIdx.x;
    if (BF16_OUT) {
        // thread t -> 8 elems of row (t>>4): one 4KB contiguous burst/block
        int r = t >> 4, c = (t & 15) * 8;
        if (nbase + r < N) {
            ushort4 o0, o1;
            o0.x = f2bf(outt[r][c + 0]); o0.y = f2bf(outt[r][c + 1]);
            o0.z = f2bf(outt[r][c + 2]); o0.w = f2bf(outt[r][c + 3]);
            o1.x = f2bf(outt[r][c + 4]); o1.y = f2bf(outt[r][c + 5]);
            o1.z = f2bf(outt[r][c + 6]); o1.w = f2bf(outt[r][c + 7]);
            ushort4* o = (ushort4*)(out_b + (size_t)(nbase + r) * D + c);
            o[0] = o0; o[1] = o1;
        }
    } else {
        // two float4 passes: 8KB contiguous burst/block
        #pragma unroll
        for (int p = 0; p < 2; ++p) {
            int e = p * 1024 + t * 4;
            int r = e >> 7, c = e & 127;
            if (nbase + r < N) {
                float4 v;
                v.x = outt[r][c + 0]; v.y = outt[r][c + 1];
                v.z = outt[r][c + 2]; v.w = outt[r][c + 3];
                *(float4*)(out_f + (size_t)nbase * D + e) = v;
            }
        }
    }
}

extern "C" void kernel_launch(void* const* d_in, const int* in_sizes, int n_in,
                              void* d_out, int out_size, void* d_ws, size_t ws_size,
                              hipStream_t stream)
{
    const float* features = (const float*)d_in[0];
    const int*   src      = (const int*)d_in[1];
    const int*   dst      = (const int*)d_in[2];
    const float* W1       = (const float*)d_in[3];
    const float* b1       = (const float*)d_in[4];
    const float* W2       = (const float*)d_in[5];
    const float* b2       = (const float*)d_in[6];
    float*       out      = (float*)d_out;

    const int N = in_sizes[0] / D;
    const int E = in_sizes[1];
    const int NB = (N + BSIZE - 1) >> BSHIFT;

    // padded bucket capacity: 2x mean, multiple of 1024;
    // bounded so packed(4B) + sbytes(1B) fit the N*D bf16 region (5B/slot).
    int cap = ((2 * (E / NB) + 2047) / 1024) * 1024;
    int cap_max = (int)(((size_t)N * D * 2 / (5 * NB)) / 1024 * 1024);
    if (cap > cap_max) cap = cap_max;

    // workspace layout
    u16*   scratch  = (u16*)d_ws;                   // N*D bf16 region (packed+sbytes)
    int*   packed   = (int*)scratch;                // NB*cap ints
    u8*    sbytes   = (u8*)(packed + (size_t)NB * cap);  // NB*cap bytes
    u16*   feat_bf  = scratch + (size_t)N * D;      // N*D bf16
    u16*   hs_bf    = feat_bf + (size_t)N * D;      // N*D bf16
    u16*   wT1      = hs_bf + (size_t)N * D;        // 16384 bf16
    u16*   wT2      = wT1 + D * D;                  // 16384 bf16
    float* norm_src = (float*)(wT2 + D * D);        // N
    float* norm_dst = norm_src + N;                 // N
    int*   iws          = (int*)(norm_dst + N);
    int*   row_ptr      = iws;                      // N+1
    int*   col          = row_ptr + N + 1;          // E
    int*   bucket_ptr   = col + E;                  // NBMAX+1
    int*   cursor_d     = bucket_ptr + NBMAX + 1;   // NBMAX
    int*   cursor_s     = cursor_d + NBMAX;         // NBMAX

    const int ebk = (E + CHUNK - 1) / CHUNK;
    const int fuse_blocks = (N + 15) / 16;

    // ---- CSR build: 4 launches total before the fused layers ----
    setup_kernel<<<129, 256, 0, stream>>>(W1, W2, wT1, wT2, cursor_d, cursor_s, NB, cap);
    scatter_direct_kernel<<<ebk, 256, 0, stream>>>(src, dst, cursor_d, cursor_s, packed, sbytes, E, cap);
    bucket_scan_kernel<<<1, NBMAX, 0, stream>>>(cursor_d, bucket_ptr, row_ptr, NB, N, E, cap);
    fine_place_kernel<<<NB, 256, 0, stream>>>(
        packed, sbytes, cursor_d, cursor_s, bucket_ptr, row_ptr,
        norm_dst, norm_src, col, features, feat_bf, N * 32, N, cap);

    // ---- layer 1 (fused aggregate+GEMM) ----
    agg_gemm_kernel<true><<<fuse_blocks, 256, 0, stream>>>(
        feat_bf, row_ptr, col, norm_src, norm_dst, wT1, b1, nullptr, hs_bf, N);

    // ---- layer 2 (fused aggregate+GEMM) ----
    agg_gemm_kernel<false><<<fuse_blocks, 256, 0, stream>>>(
        hs_bf, row_ptr, col, norm_src, norm_dst, wT2, b2, out, nullptr, N);
}